// Round 1
// baseline (958.728 us; speedup 1.0000x reference)
//
#include <hip/hip_runtime.h>
#include <hip/hip_bf16.h>
#include <math.h>

// CausalSelfAttention fused pipeline for MI355X (gfx950).
// B=4 T=2048 C=2048 H=16 HK=4 D=128 WIN=1024.
// Pipeline:
//   convert W -> bf16 (x4)
//   prep: rmsnorm(x0) + alpha/beta mix -> xq,xk,xb,x0n (bf16)
//   gemm_bt: q_pre / k_pre / v_init / cvx   (bf16 MFMA 16x16x32, 128x128 tile,
//            global_load_lds width=16 staging)
//   post_qk: rope + per-head rmsnorm *1.2 -> qh [b][h][t][d], kh [b][hk][t][d]
//   post_v : v = av*v_init + bv*cvx -> vth [b][hk][d][t] (transposed), v_init -> d_out
//   attn   : flash attention, Q-tile 128, K-tile 64, online softmax, window 1024
//   gemm_bt: y = att @ Wproj^T -> d_out (fp32)
// Workspace map (MB): 0 xq/att | 32 xk/qh | 64 xb/kh | 72 vth | 96 x0n |
//   128 vinit | 136 cvx | 144 Wqb | 152 Wkb | 154 Wvb | 156 Wpb | total 164.
// q_pre (bf16, 32MB) lives in d_out y-region; k_pre (8MB) in d_out v-region;
// both are consumed before those regions are overwritten (stream-ordered).

using bf16 = __hip_bfloat16;
typedef __attribute__((ext_vector_type(8))) short bf16x8;
typedef __attribute__((ext_vector_type(4))) float f32x4;

constexpr int Bb = 4, Ts = 2048, Cc = 2048, NH = 16, NKV = 4, Dh = 128, WIN = 1024;
constexpr float EPS = 1.1920929e-07f;

__device__ __forceinline__ void gld16(void* lds, const void* g) {
  __builtin_amdgcn_global_load_lds(
      (__attribute__((address_space(1))) unsigned int*)((void*)g),
      (__attribute__((address_space(3))) unsigned int*)lds, 16, 0, 0);
}

__device__ __forceinline__ unsigned short bfbits(float f) {
  bf16 h = __float2bfloat16(f);
  return __builtin_bit_cast(unsigned short, h);
}

__device__ __forceinline__ void store_out(float* p, float v) { *p = v; }
__device__ __forceinline__ void store_out(bf16* p, float v) { *p = __float2bfloat16(v); }

// ---------------------------------------------------------------- convert W
__global__ __launch_bounds__(256) void convert_w(const float* __restrict__ src,
                                                 bf16* __restrict__ dst, int n4) {
  int i = blockIdx.x * 256 + threadIdx.x;
  if (i < n4) {
    float4 v = ((const float4*)src)[i];
    ushort4 u;
    u.x = bfbits(v.x); u.y = bfbits(v.y); u.z = bfbits(v.z); u.w = bfbits(v.w);
    ((ushort4*)dst)[i] = u;
  }
}

// ------------------------------------------------------- prep: rmsnorm + mix
__global__ __launch_bounds__(256) void prep(
    const float* __restrict__ x, const float* __restrict__ x0,
    const float* aq_p, const float* bq_p, const float* ak_p, const float* bk_p,
    bf16* __restrict__ xq, bf16* __restrict__ xk,
    bf16* __restrict__ xb, bf16* __restrict__ x0n) {
  const int row = blockIdx.x, tid = threadIdx.x;
  const float4* xr = (const float4*)(x + (size_t)row * Cc);
  const float4* nr = (const float4*)(x0 + (size_t)row * Cc);
  float4 xa[2], na[2];
  float ss = 0.f;
#pragma unroll
  for (int j = 0; j < 2; ++j) {
    xa[j] = xr[tid + j * 256];
    na[j] = nr[tid + j * 256];
    ss += na[j].x * na[j].x + na[j].y * na[j].y + na[j].z * na[j].z + na[j].w * na[j].w;
  }
#pragma unroll
  for (int o = 32; o; o >>= 1) ss += __shfl_xor(ss, o);
  __shared__ float red[4];
  if ((tid & 63) == 0) red[tid >> 6] = ss;
  __syncthreads();
  const float rms = rsqrtf((red[0] + red[1] + red[2] + red[3]) * (1.f / Cc) + EPS);
  const float aq = *aq_p, bq = *bq_p, ak = *ak_p, bk = *bk_p;
#pragma unroll
  for (int j = 0; j < 2; ++j) {
    const size_t base = (size_t)row * Cc + (size_t)(tid + j * 256) * 4;
    float nx[4] = {na[j].x * rms, na[j].y * rms, na[j].z * rms, na[j].w * rms};
    float xv[4] = {xa[j].x, xa[j].y, xa[j].z, xa[j].w};
    ushort4 uq, uk, ub, un;
    uq.x = bfbits(aq * xv[0] + bq * nx[0]); uq.y = bfbits(aq * xv[1] + bq * nx[1]);
    uq.z = bfbits(aq * xv[2] + bq * nx[2]); uq.w = bfbits(aq * xv[3] + bq * nx[3]);
    uk.x = bfbits(ak * xv[0] + bk * nx[0]); uk.y = bfbits(ak * xv[1] + bk * nx[1]);
    uk.z = bfbits(ak * xv[2] + bk * nx[2]); uk.w = bfbits(ak * xv[3] + bk * nx[3]);
    ub.x = bfbits(xv[0]); ub.y = bfbits(xv[1]); ub.z = bfbits(xv[2]); ub.w = bfbits(xv[3]);
    un.x = bfbits(nx[0]); un.y = bfbits(nx[1]); un.z = bfbits(nx[2]); un.w = bfbits(nx[3]);
    *(ushort4*)(xq + base) = uq;
    *(ushort4*)(xk + base) = uk;
    *(ushort4*)(xb + base) = ub;
    *(ushort4*)(x0n + base) = un;
  }
}

// ------------------------------------------------ GEMM: C[m,n] = sum_k A[m,k]W[n,k]
template <typename OutT>
__global__ __launch_bounds__(256) void gemm_bt(
    const bf16* __restrict__ A, const bf16* __restrict__ W,
    OutT* __restrict__ C, int M, int N, int K) {
  __shared__ unsigned short sA[128 * 64];
  __shared__ unsigned short sB[128 * 64];
  const int tid = threadIdx.x, wave = tid >> 6, lane = tid & 63;
  const int quad = lane >> 4, l15 = lane & 15;
  const int bm = blockIdx.x * 128, bn = blockIdx.y * 128;
  const int wm = (wave >> 1) * 64, wn = (wave & 1) * 64;
  const int srow = wave * 32 + (lane >> 3);
  const int scol = (lane & 7) * 8;

  f32x4 acc[4][4] = {};

  for (int k0 = 0; k0 < K; k0 += 64) {
#pragma unroll
    for (int i = 0; i < 4; ++i) {
      gld16(&sA[(wave * 32 + i * 8) * 64], &A[(size_t)(bm + srow + i * 8) * K + k0 + scol]);
      gld16(&sB[(wave * 32 + i * 8) * 64], &W[(size_t)(bn + srow + i * 8) * K + k0 + scol]);
    }
    __syncthreads();
#pragma unroll
    for (int kk = 0; kk < 2; ++kk) {
      bf16x8 af[4], bfr[4];
#pragma unroll
      for (int t = 0; t < 4; ++t)
        af[t] = *(const bf16x8*)&sA[(wm + t * 16 + l15) * 64 + kk * 32 + quad * 8];
#pragma unroll
      for (int t = 0; t < 4; ++t)
        bfr[t] = *(const bf16x8*)&sB[(wn + t * 16 + l15) * 64 + kk * 32 + quad * 8];
#pragma unroll
      for (int tm = 0; tm < 4; ++tm)
#pragma unroll
        for (int tn = 0; tn < 4; ++tn)
          acc[tm][tn] = __builtin_amdgcn_mfma_f32_16x16x32_bf16(af[tm], bfr[tn], acc[tm][tn], 0, 0, 0);
    }
    __syncthreads();
  }
#pragma unroll
  for (int tm = 0; tm < 4; ++tm)
#pragma unroll
    for (int tn = 0; tn < 4; ++tn)
#pragma unroll
      for (int r = 0; r < 4; ++r) {
        const int row = bm + wm + tm * 16 + quad * 4 + r;
        const int col = bn + wn + tn * 16 + l15;
        store_out(&C[(size_t)row * N + col], acc[tm][tn][r]);
      }
}

// --------------------------------------------- rope + per-head rmsnorm * 1.2
__global__ __launch_bounds__(256) void post_qk(
    const bf16* __restrict__ pre, const float* __restrict__ cosp,
    const float* __restrict__ sinp, bf16* __restrict__ outh, int nh) {
  const int wid = blockIdx.x * 4 + (threadIdx.x >> 6);
  const int lane = threadIdx.x & 63;
  const int h = wid % nh;
  const int bt = wid / nh;
  const int t = bt & (Ts - 1);
  const int b = bt >> 11;
  const size_t src = (size_t)bt * (size_t)(nh * Dh) + (size_t)h * Dh;
  float x1 = __bfloat162float(pre[src + lane]);
  float x2 = __bfloat162float(pre[src + 64 + lane]);
  float c = cosp[t * 64 + lane], s = sinp[t * 64 + lane];
  float o1 = x1 * c + x2 * s;
  float o2 = x2 * c - x1 * s;
  float ss = o1 * o1 + o2 * o2;
#pragma unroll
  for (int o = 32; o; o >>= 1) ss += __shfl_xor(ss, o);
  const float r = rsqrtf(ss * (1.f / Dh) + EPS) * 1.2f;
  const size_t dst = ((size_t)(b * nh + h) * Ts + t) * Dh;
  outh[dst + lane] = __float2bfloat16(o1 * r);
  outh[dst + 64 + lane] = __float2bfloat16(o2 * r);
}

// ------------------------- v mix + transpose to [b][hk][d][t]; v_init -> out
__global__ __launch_bounds__(256) void post_v(
    const bf16* __restrict__ vinit, const bf16* __restrict__ cvx,
    const float* av_p, const float* bv_p,
    bf16* __restrict__ vth, float* __restrict__ vout) {
  __shared__ unsigned short vt[128 * 65];
  const int t0 = blockIdx.x * 64;
  const int b = blockIdx.y >> 2, hk = blockIdx.y & 3;
  const float av = *av_p, bv = *bv_p;
  const int tid = threadIdx.x;
  for (int j = 0; j < 32; ++j) {
    const int e = j * 256 + tid;
    const int tl = e >> 7, d = e & 127;
    const size_t src = (size_t)(b * Ts + t0 + tl) * (NKV * Dh) + hk * Dh + d;
    const float vi = __bfloat162float(vinit[src]);
    const float cv = __bfloat162float(cvx[src]);
    vout[src] = vi;
    vt[d * 65 + tl] = bfbits(av * vi + bv * cv);
  }
  __syncthreads();
#pragma unroll
  for (int j = 0; j < 4; ++j) {
    const int g = j * 256 + tid;
    const int d = g >> 3, t8 = (g & 7) * 8;
    const unsigned short* p = &vt[d * 65 + t8];
    uint4 u;
    u.x = p[0] | ((unsigned int)p[1] << 16);
    u.y = p[2] | ((unsigned int)p[3] << 16);
    u.z = p[4] | ((unsigned int)p[5] << 16);
    u.w = p[6] | ((unsigned int)p[7] << 16);
    *(uint4*)&vth[((size_t)(b * NKV + hk) * Dh + d) * Ts + t0 + t8] = u;
  }
}

// -------------------------------------------------------- flash attention
__global__ __launch_bounds__(256) void attn(
    const bf16* __restrict__ qh, const bf16* __restrict__ kh,
    const bf16* __restrict__ vth, bf16* __restrict__ att) {
  __shared__ unsigned short sQ[128 * 128];  // reused as P[128][64] after Q->regs
  __shared__ unsigned short sK[64 * 128];   // [j][d]
  __shared__ unsigned short sV[128 * 64];   // [d][j]

  const int tid = threadIdx.x, wave = tid >> 6, lane = tid & 63;
  const int quad = lane >> 4, l15 = lane & 15;
  const int q0 = blockIdx.x * 128;
  const int b = blockIdx.y >> 4, h = blockIdx.y & 15, hk = h >> 2;

  const bf16* Qp = qh + (size_t)(b * NH + h) * Ts * Dh;
  const bf16* Kp = kh + (size_t)(b * NKV + hk) * Ts * Dh;
  const bf16* Vp = vth + (size_t)(b * NKV + hk) * Dh * Ts;

  {
    const int rr = lane >> 4, c0 = (lane & 15) * 8;
#pragma unroll
    for (int i = 0; i < 8; ++i)
      gld16(&sQ[(wave * 32 + i * 4) * 128],
            &Qp[(size_t)(q0 + wave * 32 + i * 4 + rr) * Dh + c0]);
  }
  __syncthreads();
  bf16x8 qf[2][4];
#pragma unroll
  for (int tm = 0; tm < 2; ++tm)
#pragma unroll
    for (int kk = 0; kk < 4; ++kk)
      qf[tm][kk] = *(const bf16x8*)&sQ[(wave * 32 + tm * 16 + l15) * 128 + kk * 32 + quad * 8];
  __syncthreads();  // all Q reads done before sQ is reused as P

  f32x4 of[2][8] = {};
  float m_i[2][4], l_i[2][4];
#pragma unroll
  for (int tm = 0; tm < 2; ++tm)
#pragma unroll
    for (int r = 0; r < 4; ++r) { m_i[tm][r] = -__builtin_inff(); l_i[tm][r] = 0.f; }

  const int jt_lo = q0 >= WIN ? (q0 - WIN) >> 6 : 0;
  const int jt_hi = (q0 + 127) >> 6;
  const int qw = q0 + wave * 32;

  for (int jt = jt_lo; jt <= jt_hi; ++jt) {
    const int j0 = jt << 6;
    __syncthreads();
    {
      const int rr = lane >> 4, c0 = (lane & 15) * 8;
#pragma unroll
      for (int i = 0; i < 4; ++i)
        gld16(&sK[(wave * 16 + i * 4) * 128],
              &Kp[(size_t)(j0 + wave * 16 + i * 4 + rr) * Dh + c0]);
      const int rr2 = lane >> 3, c2 = (lane & 7) * 8;
#pragma unroll
      for (int i = 0; i < 4; ++i)
        gld16(&sV[(wave * 32 + i * 8) * 64],
              &Vp[(size_t)(wave * 32 + i * 8 + rr2) * Ts + j0 + c2]);
    }
    __syncthreads();

    // per-wave skip of fully-masked tiles (barrier counts stay uniform)
    if (j0 > qw + 31 || qw > j0 + 63 + WIN) continue;

    f32x4 sf[2][4];
#pragma unroll
    for (int tn = 0; tn < 4; ++tn) {
      bf16x8 kf[4];
#pragma unroll
      for (int kk = 0; kk < 4; ++kk)
        kf[kk] = *(const bf16x8*)&sK[(tn * 16 + l15) * 128 + kk * 32 + quad * 8];
#pragma unroll
      for (int tm = 0; tm < 2; ++tm) {
        f32x4 a = {};
#pragma unroll
        for (int kk = 0; kk < 4; ++kk)
          a = __builtin_amdgcn_mfma_f32_16x16x32_bf16(qf[tm][kk], kf[kk], a, 0, 0, 0);
        sf[tm][tn] = a;
      }
    }

    constexpr float scale = 0.08838834764831845f;
    float mcur[2][4];
#pragma unroll
    for (int tm = 0; tm < 2; ++tm)
#pragma unroll
      for (int r = 0; r < 4; ++r) mcur[tm][r] = -__builtin_inff();
#pragma unroll
    for (int tm = 0; tm < 2; ++tm)
#pragma unroll
      for (int tn = 0; tn < 4; ++tn) {
        const int j = j0 + tn * 16 + l15;
#pragma unroll
        for (int r = 0; r < 4; ++r) {
          const int qr = qw + tm * 16 + quad * 4 + r;
          float s = sf[tm][tn][r] * scale;
          s = (j <= qr && qr - j <= WIN) ? s : -__builtin_inff();
          sf[tm][tn][r] = s;
          mcur[tm][r] = fmaxf(mcur[tm][r], s);
        }
      }
#pragma unroll
    for (int tm = 0; tm < 2; ++tm)
#pragma unroll
      for (int r = 0; r < 4; ++r) {
        float v = mcur[tm][r];
        v = fmaxf(v, __shfl_xor(v, 1));
        v = fmaxf(v, __shfl_xor(v, 2));
        v = fmaxf(v, __shfl_xor(v, 4));
        v = fmaxf(v, __shfl_xor(v, 8));
        const float mn = fmaxf(m_i[tm][r], v);
        const float al = __expf(m_i[tm][r] - mn);
        m_i[tm][r] = mn;
        mcur[tm][r] = al;  // now holds alpha
      }

    float rsum[2][4] = {};
#pragma unroll
    for (int tm = 0; tm < 2; ++tm)
#pragma unroll
      for (int tn = 0; tn < 4; ++tn)
#pragma unroll
        for (int r = 0; r < 4; ++r) {
          const float p = __expf(sf[tm][tn][r] - m_i[tm][r]);
          rsum[tm][r] += p;
          sQ[(wave * 32 + tm * 16 + quad * 4 + r) * 64 + tn * 16 + l15] = bfbits(p);
        }
#pragma unroll
    for (int tm = 0; tm < 2; ++tm)
#pragma unroll
      for (int r = 0; r < 4; ++r) {
        float v = rsum[tm][r];
        v += __shfl_xor(v, 1); v += __shfl_xor(v, 2);
        v += __shfl_xor(v, 4); v += __shfl_xor(v, 8);
        l_i[tm][r] = l_i[tm][r] * mcur[tm][r] + v;
      }
#pragma unroll
    for (int tm = 0; tm < 2; ++tm)
#pragma unroll
      for (int dn = 0; dn < 8; ++dn)
#pragma unroll
        for (int r = 0; r < 4; ++r) of[tm][dn][r] *= mcur[tm][r];

#pragma unroll
    for (int kkp = 0; kkp < 2; ++kkp) {
      bf16x8 ap[2];
#pragma unroll
      for (int tm = 0; tm < 2; ++tm)
        ap[tm] = *(const bf16x8*)&sQ[(wave * 32 + tm * 16 + l15) * 64 + kkp * 32 + quad * 8];
#pragma unroll
      for (int dn = 0; dn < 8; ++dn) {
        bf16x8 vf = *(const bf16x8*)&sV[(dn * 16 + l15) * 64 + kkp * 32 + quad * 8];
        of[0][dn] = __builtin_amdgcn_mfma_f32_16x16x32_bf16(ap[0], vf, of[0][dn], 0, 0, 0);
        of[1][dn] = __builtin_amdgcn_mfma_f32_16x16x32_bf16(ap[1], vf, of[1][dn], 0, 0, 0);
      }
    }
  }

#pragma unroll
  for (int tm = 0; tm < 2; ++tm)
#pragma unroll
    for (int r = 0; r < 4; ++r) {
      const float inv = 1.f / l_i[tm][r];
      const int qr = qw + tm * 16 + quad * 4 + r;
      bf16* dst = att + (size_t)(b * Ts + qr) * (NH * Dh) + h * Dh;
#pragma unroll
      for (int dn = 0; dn < 8; ++dn)
        dst[dn * 16 + l15] = __float2bfloat16(of[tm][dn][r] * inv);
    }
}

// ------------------------------------------------------------------ launch
extern "C" void kernel_launch(void* const* d_in, const int* in_sizes, int n_in,
                              void* d_out, int out_size, void* d_ws, size_t ws_size,
                              hipStream_t stream) {
  const float* x = (const float*)d_in[0];
  const float* x0 = (const float*)d_in[1];
  const float* cosp = (const float*)d_in[3];
  const float* sinp = (const float*)d_in[4];
  const float* Wq = (const float*)d_in[5];
  const float* Wk = (const float*)d_in[6];
  const float* Wv = (const float*)d_in[7];
  const float* Wp = (const float*)d_in[8];
  const float* aq = (const float*)d_in[9];
  const float* bq = (const float*)d_in[10];
  const float* ak = (const float*)d_in[11];
  const float* bk = (const float*)d_in[12];
  const float* av = (const float*)d_in[13];
  const float* bv = (const float*)d_in[14];

  char* ws = (char*)d_ws;
  const size_t MB = 1024ull * 1024;
  bf16* xq = (bf16*)(ws + 0 * MB);
  bf16* xk = (bf16*)(ws + 32 * MB);
  bf16* xb = (bf16*)(ws + 64 * MB);
  bf16* x0n = (bf16*)(ws + 96 * MB);
  bf16* vinit = (bf16*)(ws + 128 * MB);
  bf16* cvx = (bf16*)(ws + 136 * MB);
  bf16* Wqb = (bf16*)(ws + 144 * MB);
  bf16* Wkb = (bf16*)(ws + 152 * MB);
  bf16* Wvb = (bf16*)(ws + 154 * MB);
  bf16* Wpb = (bf16*)(ws + 156 * MB);
  bf16* att = xq;                       // reuse (xq dead after Q-GEMM)
  bf16* qh = xk;                        // reuse (xk dead after K-GEMM)
  bf16* kh = xb;                        // reuse (xb dead after V-GEMM)
  bf16* vth = (bf16*)(ws + 72 * MB);    // inside xb region

  float* y = (float*)d_out;
  float* vout = (float*)d_out + (size_t)Bb * Ts * Cc;
  bf16* q_pre = (bf16*)d_out;           // parked in y region (overwritten last)
  bf16* k_pre = (bf16*)vout;            // parked in v_init region (overwritten by post_v)

  convert_w<<<4096, 256, 0, stream>>>(Wq, Wqb, 1048576);
  convert_w<<<1024, 256, 0, stream>>>(Wk, Wkb, 262144);
  convert_w<<<1024, 256, 0, stream>>>(Wv, Wvb, 262144);
  convert_w<<<4096, 256, 0, stream>>>(Wp, Wpb, 1048576);

  prep<<<8192, 256, 0, stream>>>(x, x0, aq, bq, ak, bk, xq, xk, xb, x0n);

  gemm_bt<<<dim3(64, 16), 256, 0, stream>>>(xq, Wqb, q_pre, 8192, 2048, 2048);
  gemm_bt<<<dim3(64, 4), 256, 0, stream>>>(xk, Wkb, k_pre, 8192, 512, 2048);
  gemm_bt<<<dim3(64, 4), 256, 0, stream>>>(xb, Wvb, vinit, 8192, 512, 2048);
  gemm_bt<<<dim3(64, 4), 256, 0, stream>>>(x0n, Wvb, cvx, 8192, 512, 2048);

  post_qk<<<32768, 256, 0, stream>>>(q_pre, cosp, sinp, qh, NH);
  post_qk<<<8192, 256, 0, stream>>>(k_pre, cosp, sinp, kh, NKV);
  post_v<<<dim3(32, 16), 256, 0, stream>>>(vinit, cvx, av, bv, vth, vout);

  attn<<<dim3(16, 64), 256, 0, stream>>>(qh, kh, vth, att);

  gemm_bt<<<dim3(64, 16), 256, 0, stream>>>(att, Wpb, y, 8192, 2048, 2048);
}

// Round 2
// 790.502 us; speedup vs baseline: 1.2128x; 1.2128x over previous
//
#include <hip/hip_runtime.h>
#include <hip/hip_bf16.h>
#include <math.h>

// CausalSelfAttention fused pipeline for MI355X (gfx950).
// B=4 T=2048 C=2048 H=16 HK=4 D=128 WIN=1024.
// Round 2: attn rewritten (S^T trick, register-resident P via 16x16x16 MFMA,
// XOR-swizzled K/V staging, no sQ -> 32KB LDS); small GEMMs batched (grid.z=3).

using bf16 = __hip_bfloat16;
typedef __attribute__((ext_vector_type(8))) short bf16x8;
typedef __attribute__((ext_vector_type(4))) short bf16x4;
typedef __attribute__((ext_vector_type(4))) float f32x4;

constexpr int Bb = 4, Ts = 2048, Cc = 2048, NH = 16, NKV = 4, Dh = 128, WIN = 1024;
constexpr float EPS = 1.1920929e-07f;

__device__ __forceinline__ void gld16(void* lds, const void* g) {
  __builtin_amdgcn_global_load_lds(
      (__attribute__((address_space(1))) unsigned int*)((void*)g),
      (__attribute__((address_space(3))) unsigned int*)lds, 16, 0, 0);
}

__device__ __forceinline__ unsigned short bfbits(float f) {
  bf16 h = __float2bfloat16(f);
  return __builtin_bit_cast(unsigned short, h);
}

__device__ __forceinline__ void store_out(float* p, float v) { *p = v; }
__device__ __forceinline__ void store_out(bf16* p, float v) { *p = __float2bfloat16(v); }

// PV micro-op: D[m=q][n=d] += P(k=quad*4+0..3) * V(k=quad*4+0..3)
__device__ __forceinline__ f32x4 mfma16(bf16x4 a, bf16x4 b, f32x4 c) {
#if __has_builtin(__builtin_amdgcn_mfma_f32_16x16x16bf16_1k)
  return __builtin_amdgcn_mfma_f32_16x16x16bf16_1k(a, b, c, 0, 0, 0);
#else
  bf16x8 a8 = {a[0], a[1], a[2], a[3], 0, 0, 0, 0};
  bf16x8 b8 = {b[0], b[1], b[2], b[3], 0, 0, 0, 0};
  return __builtin_amdgcn_mfma_f32_16x16x32_bf16(a8, b8, c, 0, 0, 0);
#endif
}

// ---------------------------------------------------------------- convert W
__global__ __launch_bounds__(256) void convert_w(const float* __restrict__ src,
                                                 bf16* __restrict__ dst, int n4) {
  int i = blockIdx.x * 256 + threadIdx.x;
  if (i < n4) {
    float4 v = ((const float4*)src)[i];
    ushort4 u;
    u.x = bfbits(v.x); u.y = bfbits(v.y); u.z = bfbits(v.z); u.w = bfbits(v.w);
    ((ushort4*)dst)[i] = u;
  }
}

// ------------------------------------------------------- prep: rmsnorm + mix
__global__ __launch_bounds__(256) void prep(
    const float* __restrict__ x, const float* __restrict__ x0,
    const float* aq_p, const float* bq_p, const float* ak_p, const float* bk_p,
    bf16* __restrict__ xq, bf16* __restrict__ xk,
    bf16* __restrict__ xb, bf16* __restrict__ x0n) {
  const int row = blockIdx.x, tid = threadIdx.x;
  const float4* xr = (const float4*)(x + (size_t)row * Cc);
  const float4* nr = (const float4*)(x0 + (size_t)row * Cc);
  float4 xa[2], na[2];
  float ss = 0.f;
#pragma unroll
  for (int j = 0; j < 2; ++j) {
    xa[j] = xr[tid + j * 256];
    na[j] = nr[tid + j * 256];
    ss += na[j].x * na[j].x + na[j].y * na[j].y + na[j].z * na[j].z + na[j].w * na[j].w;
  }
#pragma unroll
  for (int o = 32; o; o >>= 1) ss += __shfl_xor(ss, o);
  __shared__ float red[4];
  if ((tid & 63) == 0) red[tid >> 6] = ss;
  __syncthreads();
  const float rms = rsqrtf((red[0] + red[1] + red[2] + red[3]) * (1.f / Cc) + EPS);
  const float aq = *aq_p, bq = *bq_p, ak = *ak_p, bk = *bk_p;
#pragma unroll
  for (int j = 0; j < 2; ++j) {
    const size_t base = (size_t)row * Cc + (size_t)(tid + j * 256) * 4;
    float nx[4] = {na[j].x * rms, na[j].y * rms, na[j].z * rms, na[j].w * rms};
    float xv[4] = {xa[j].x, xa[j].y, xa[j].z, xa[j].w};
    ushort4 uq, uk, ub, un;
    uq.x = bfbits(aq * xv[0] + bq * nx[0]); uq.y = bfbits(aq * xv[1] + bq * nx[1]);
    uq.z = bfbits(aq * xv[2] + bq * nx[2]); uq.w = bfbits(aq * xv[3] + bq * nx[3]);
    uk.x = bfbits(ak * xv[0] + bk * nx[0]); uk.y = bfbits(ak * xv[1] + bk * nx[1]);
    uk.z = bfbits(ak * xv[2] + bk * nx[2]); uk.w = bfbits(ak * xv[3] + bk * nx[3]);
    ub.x = bfbits(xv[0]); ub.y = bfbits(xv[1]); ub.z = bfbits(xv[2]); ub.w = bfbits(xv[3]);
    un.x = bfbits(nx[0]); un.y = bfbits(nx[1]); un.z = bfbits(nx[2]); un.w = bfbits(nx[3]);
    *(ushort4*)(xq + base) = uq;
    *(ushort4*)(xk + base) = uk;
    *(ushort4*)(xb + base) = ub;
    *(ushort4*)(x0n + base) = un;
  }
}

// ------------------------------------------------ GEMM body (m97 structure)
template <typename OutT>
__device__ __forceinline__ void gemm_body(
    const bf16* __restrict__ A, const bf16* __restrict__ W,
    OutT* __restrict__ C, int N, int K) {
  __shared__ unsigned short sA[128 * 64];
  __shared__ unsigned short sB[128 * 64];
  const int tid = threadIdx.x, wave = tid >> 6, lane = tid & 63;
  const int quad = lane >> 4, l15 = lane & 15;
  const int bm = blockIdx.x * 128, bn = blockIdx.y * 128;
  const int wm = (wave >> 1) * 64, wn = (wave & 1) * 64;
  const int srow = wave * 32 + (lane >> 3);
  const int scol = (lane & 7) * 8;

  f32x4 acc[4][4] = {};

  for (int k0 = 0; k0 < K; k0 += 64) {
#pragma unroll
    for (int i = 0; i < 4; ++i) {
      gld16(&sA[(wave * 32 + i * 8) * 64], &A[(size_t)(bm + srow + i * 8) * K + k0 + scol]);
      gld16(&sB[(wave * 32 + i * 8) * 64], &W[(size_t)(bn + srow + i * 8) * K + k0 + scol]);
    }
    __syncthreads();
#pragma unroll
    for (int kk = 0; kk < 2; ++kk) {
      bf16x8 af[4], bfr[4];
#pragma unroll
      for (int t = 0; t < 4; ++t)
        af[t] = *(const bf16x8*)&sA[(wm + t * 16 + l15) * 64 + kk * 32 + quad * 8];
#pragma unroll
      for (int t = 0; t < 4; ++t)
        bfr[t] = *(const bf16x8*)&sB[(wn + t * 16 + l15) * 64 + kk * 32 + quad * 8];
#pragma unroll
      for (int tm = 0; tm < 4; ++tm)
#pragma unroll
        for (int tn = 0; tn < 4; ++tn)
          acc[tm][tn] = __builtin_amdgcn_mfma_f32_16x16x32_bf16(af[tm], bfr[tn], acc[tm][tn], 0, 0, 0);
    }
    __syncthreads();
  }
#pragma unroll
  for (int tm = 0; tm < 4; ++tm)
#pragma unroll
    for (int tn = 0; tn < 4; ++tn)
#pragma unroll
      for (int r = 0; r < 4; ++r) {
        const int row = bm + wm + tm * 16 + quad * 4 + r;
        const int col = bn + wn + tn * 16 + l15;
        store_out(&C[(size_t)row * N + col], acc[tm][tn][r]);
      }
}

template <typename OutT>
__global__ __launch_bounds__(256) void gemm_bt(
    const bf16* __restrict__ A, const bf16* __restrict__ W,
    OutT* __restrict__ C, int N, int K) {
  gemm_body<OutT>(A, W, C, N, K);
}

struct GemmTriple { const bf16* A; const bf16* W; bf16* C; };
struct GemmTriple3 { GemmTriple t[3]; };

__global__ __launch_bounds__(256) void gemm_bt3(GemmTriple3 g, int N, int K) {
  const GemmTriple tr = g.t[blockIdx.z];
  gemm_body<bf16>(tr.A, tr.W, tr.C, N, K);
}

// --------------------------------------------- rope + per-head rmsnorm * mult
__global__ __launch_bounds__(256) void post_qk(
    const bf16* __restrict__ pre, const float* __restrict__ cosp,
    const float* __restrict__ sinp, bf16* __restrict__ outh, int nh, float mult) {
  const int wid = blockIdx.x * 4 + (threadIdx.x >> 6);
  const int lane = threadIdx.x & 63;
  const int h = wid % nh;
  const int bt = wid / nh;
  const int t = bt & (Ts - 1);
  const int b = bt >> 11;
  const size_t src = (size_t)bt * (size_t)(nh * Dh) + (size_t)h * Dh;
  float x1 = __bfloat162float(pre[src + lane]);
  float x2 = __bfloat162float(pre[src + 64 + lane]);
  float c = cosp[t * 64 + lane], s = sinp[t * 64 + lane];
  float o1 = x1 * c + x2 * s;
  float o2 = x2 * c - x1 * s;
  float ss = o1 * o1 + o2 * o2;
#pragma unroll
  for (int o = 32; o; o >>= 1) ss += __shfl_xor(ss, o);
  const float r = rsqrtf(ss * (1.f / Dh) + EPS) * mult;
  const size_t dst = ((size_t)(b * nh + h) * Ts + t) * Dh;
  outh[dst + lane] = __float2bfloat16(o1 * r);
  outh[dst + 64 + lane] = __float2bfloat16(o2 * r);
}

// ------------------------- v mix + transpose to [b][hk][d][t]; v_init -> out
__global__ __launch_bounds__(256) void post_v(
    const bf16* __restrict__ vinit, const bf16* __restrict__ cvx,
    const float* av_p, const float* bv_p,
    bf16* __restrict__ vth, float* __restrict__ vout) {
  __shared__ unsigned short vt[128 * 65];
  const int t0 = blockIdx.x * 64;
  const int b = blockIdx.y >> 2, hk = blockIdx.y & 3;
  const float av = *av_p, bv = *bv_p;
  const int tid = threadIdx.x;
  for (int j = 0; j < 32; ++j) {
    const int e = j * 256 + tid;
    const int tl = e >> 7, d = e & 127;
    const size_t src = (size_t)(b * Ts + t0 + tl) * (NKV * Dh) + hk * Dh + d;
    const float vi = __bfloat162float(vinit[src]);
    const float cv = __bfloat162float(cvx[src]);
    vout[src] = vi;
    vt[d * 65 + tl] = bfbits(av * vi + bv * cv);
  }
  __syncthreads();
#pragma unroll
  for (int j = 0; j < 4; ++j) {
    const int g = j * 256 + tid;
    const int d = g >> 3, t8 = (g & 7) * 8;
    const unsigned short* p = &vt[d * 65 + t8];
    uint4 u;
    u.x = p[0] | ((unsigned int)p[1] << 16);
    u.y = p[2] | ((unsigned int)p[3] << 16);
    u.z = p[4] | ((unsigned int)p[5] << 16);
    u.w = p[6] | ((unsigned int)p[7] << 16);
    *(uint4*)&vth[((size_t)(b * NKV + hk) * Dh + d) * Ts + t0 + t8] = u;
  }
}

// -------------------------------------------------------- flash attention v2
// S^T = mfma(kf, qf): lane l15 = q, quad*4+r = j  -> P is directly the
// A-fragment of 16x16x16 PV MFMA. No P LDS round-trip. Softmax state per-lane.
__global__ __launch_bounds__(256) void attn(
    const bf16* __restrict__ qh, const bf16* __restrict__ kh,
    const bf16* __restrict__ vth, bf16* __restrict__ att) {
  __shared__ unsigned short sK[64 * 128];  // [j][d], 16B-granule XOR-swizzled by (j&15)
  __shared__ unsigned short sV[128 * 64];  // [d][j], 16B-granule XOR-swizzled by (d&7)

  const int tid = threadIdx.x, wave = tid >> 6, lane = tid & 63;
  const int quad = lane >> 4, l15 = lane & 15;
  const int q0 = blockIdx.x * 128;
  const int b = blockIdx.y >> 4, h = blockIdx.y & 15, hk = h >> 2;

  const bf16* Qp = qh + (size_t)(b * NH + h) * Ts * Dh;
  const bf16* Kp = kh + (size_t)(b * NKV + hk) * Ts * Dh;
  const bf16* Vp = vth + (size_t)(b * NKV + hk) * Dh * Ts;

  const int qw = q0 + wave * 32;

  // Q fragments straight from global (read once per block).
  bf16x8 qf[2][4];
#pragma unroll
  for (int tm = 0; tm < 2; ++tm)
#pragma unroll
    for (int kk = 0; kk < 4; ++kk)
      qf[tm][kk] = *(const bf16x8*)&Qp[(size_t)(qw + tm * 16 + l15) * Dh + kk * 32 + quad * 8];

  f32x4 of[2][8] = {};
  float m_i[2] = {-__builtin_inff(), -__builtin_inff()};
  float l_i[2] = {0.f, 0.f};

  const int krow = lane >> 4, kgp = lane & 15;  // K staging: 4 rows x 16 granules / 1KB
  const int vrow = lane >> 3, vgp = lane & 7;   // V staging: 8 rows x 8 granules / 1KB

  const int jt_lo = q0 >= WIN ? (q0 - WIN) >> 6 : 0;
  const int jt_hi = (q0 + 127) >> 6;

  for (int jt = jt_lo; jt <= jt_hi; ++jt) {
    const int j0 = jt << 6;
    __syncthreads();
#pragma unroll
    for (int i = 0; i < 4; ++i) {
      const int row = wave * 16 + i * 4 + krow;
      gld16(&sK[(wave * 16 + i * 4) * 128],
            &Kp[(size_t)(j0 + row) * Dh + (kgp ^ (row & 15)) * 8]);
      const int d = wave * 32 + i * 8 + vrow;
      gld16(&sV[(wave * 32 + i * 8) * 64],
            &Vp[(size_t)d * Ts + j0 + (vgp ^ (d & 7)) * 8]);
    }
    __syncthreads();

    // per-wave skip of fully-masked tiles (barrier counts stay uniform)
    if (j0 > qw + 31 || qw > j0 + 63 + WIN) continue;

    // S^T: sfT[tn][tm][r] = S[q = qw+tm*16+l15][j = j0+tn*16+quad*4+r]
    f32x4 sfT[4][2];
#pragma unroll
    for (int tn = 0; tn < 4; ++tn) {
      bf16x8 kf[4];
#pragma unroll
      for (int kk = 0; kk < 4; ++kk)
        kf[kk] = *(const bf16x8*)&sK[(tn * 16 + l15) * 128 + (((kk * 4 + quad) ^ l15) * 8)];
#pragma unroll
      for (int tm = 0; tm < 2; ++tm) {
        f32x4 a = {};
#pragma unroll
        for (int kk = 0; kk < 4; ++kk)
          a = __builtin_amdgcn_mfma_f32_16x16x32_bf16(kf[kk], qf[tm][kk], a, 0, 0, 0);
        sfT[tn][tm] = a;
      }
    }

    float alpha[2];
    bf16x4 pf[2][4];
#pragma unroll
    for (int tm = 0; tm < 2; ++tm) {
      const int dq = (qw + tm * 16 + l15) - (j0 + quad * 4);  // q - j (r=0,tn=0)
      float mloc = -__builtin_inff();
#pragma unroll
      for (int tn = 0; tn < 4; ++tn)
#pragma unroll
        for (int r = 0; r < 4; ++r) {
          const unsigned diff = (unsigned)(dq - tn * 16 - r);
          float s = (diff <= (unsigned)WIN) ? sfT[tn][tm][r] : -__builtin_inff();
          sfT[tn][tm][r] = s;
          mloc = fmaxf(mloc, s);
        }
      mloc = fmaxf(mloc, __shfl_xor(mloc, 16));
      mloc = fmaxf(mloc, __shfl_xor(mloc, 32));
      const float mnew = fmaxf(m_i[tm], mloc);
      alpha[tm] = __builtin_amdgcn_exp2f(m_i[tm] - mnew);
      m_i[tm] = mnew;
      float rs = 0.f;
#pragma unroll
      for (int tn = 0; tn < 4; ++tn) {
        bf16x4 p4;
#pragma unroll
        for (int r = 0; r < 4; ++r) {
          const float p = __builtin_amdgcn_exp2f(sfT[tn][tm][r] - mnew);
          rs += p;
          p4[r] = (short)bfbits(p);
        }
        pf[tm][tn] = p4;
      }
      rs += __shfl_xor(rs, 16);
      rs += __shfl_xor(rs, 32);
      l_i[tm] = l_i[tm] * alpha[tm] + rs;
    }

    // rescale O by alpha (alpha lives at lane l15=q; O rows are quad*4+r)
#pragma unroll
    for (int tm = 0; tm < 2; ++tm) {
      float ar[4];
#pragma unroll
      for (int r = 0; r < 4; ++r) ar[r] = __shfl(alpha[tm], quad * 4 + r);
#pragma unroll
      for (int dn = 0; dn < 8; ++dn)
#pragma unroll
        for (int r = 0; r < 4; ++r) of[tm][dn][r] *= ar[r];
    }

    // PV: O[q][d] += P * V, K=16 per tn-subtile, P stays in registers
#pragma unroll
    for (int tn = 0; tn < 4; ++tn) {
      const int gsw = (tn * 2) ^ (l15 & 7);
#pragma unroll
      for (int dn = 0; dn < 8; ++dn) {
        const int d = dn * 16 + l15;
        const bf16x4 vf = *(const bf16x4*)&sV[d * 64 + ((gsw ^ (quad >> 1)) * 8) + (quad & 1) * 4];
        of[0][dn] = mfma16(pf[0][tn], vf, of[0][dn]);
        of[1][dn] = mfma16(pf[1][tn], vf, of[1][dn]);
      }
    }
  }

  // epilogue: normalize by l (per-row via shuffle), write att [b][t][h][d]
#pragma unroll
  for (int tm = 0; tm < 2; ++tm) {
#pragma unroll
    for (int r = 0; r < 4; ++r) {
      const float lr = __shfl(l_i[tm], quad * 4 + r);
      const float inv = 1.f / lr;
      const int qr = qw + tm * 16 + quad * 4 + r;
      bf16* dst = att + (size_t)(b * Ts + qr) * (NH * Dh) + h * Dh;
#pragma unroll
      for (int dn = 0; dn < 8; ++dn)
        dst[dn * 16 + l15] = __float2bfloat16(of[tm][dn][r] * inv);
    }
  }
}

// ------------------------------------------------------------------ launch
extern "C" void kernel_launch(void* const* d_in, const int* in_sizes, int n_in,
                              void* d_out, int out_size, void* d_ws, size_t ws_size,
                              hipStream_t stream) {
  const float* x = (const float*)d_in[0];
  const float* x0 = (const float*)d_in[1];
  const float* cosp = (const float*)d_in[3];
  const float* sinp = (const float*)d_in[4];
  const float* Wq = (const float*)d_in[5];
  const float* Wk = (const float*)d_in[6];
  const float* Wv = (const float*)d_in[7];
  const float* Wp = (const float*)d_in[8];
  const float* aq = (const float*)d_in[9];
  const float* bq = (const float*)d_in[10];
  const float* ak = (const float*)d_in[11];
  const float* bk = (const float*)d_in[12];
  const float* av = (const float*)d_in[13];
  const float* bv = (const float*)d_in[14];

  char* ws = (char*)d_ws;
  const size_t MB = 1024ull * 1024;
  bf16* xq = (bf16*)(ws + 0 * MB);
  bf16* xk = (bf16*)(ws + 32 * MB);
  bf16* xb = (bf16*)(ws + 64 * MB);
  bf16* x0n = (bf16*)(ws + 96 * MB);
  bf16* vinit = (bf16*)(ws + 128 * MB);
  bf16* cvx = (bf16*)(ws + 136 * MB);
  bf16* Wqb = (bf16*)(ws + 144 * MB);
  bf16* Wkb = (bf16*)(ws + 152 * MB);
  bf16* Wvb = (bf16*)(ws + 154 * MB);
  bf16* Wpb = (bf16*)(ws + 156 * MB);
  bf16* att = xq;                     // reuse (xq dead after Q-GEMM)
  bf16* qh = xk;                      // reuse (xk dead after K-GEMM)
  bf16* kh = xb;                      // reuse (xb dead after V-GEMM)
  bf16* vth = (bf16*)(ws + 72 * MB);  // inside xb region

  float* y = (float*)d_out;
  float* vout = (float*)d_out + (size_t)Bb * Ts * Cc;
  bf16* q_pre = (bf16*)d_out;  // parked in y region (overwritten last)
  bf16* k_pre = (bf16*)vout;   // parked in v_init region (overwritten by post_v)

  convert_w<<<4096, 256, 0, stream>>>(Wq, Wqb, 1048576);
  convert_w<<<1024, 256, 0, stream>>>(Wk, Wkb, 262144);
  convert_w<<<1024, 256, 0, stream>>>(Wv, Wvb, 262144);
  convert_w<<<4096, 256, 0, stream>>>(Wp, Wpb, 1048576);

  prep<<<8192, 256, 0, stream>>>(x, x0, aq, bq, ak, bk, xq, xk, xb, x0n);

  gemm_bt<bf16><<<dim3(64, 16), 256, 0, stream>>>(xq, Wqb, q_pre, 2048, 2048);

  GemmTriple3 g3;
  g3.t[0] = {xk, Wkb, k_pre};
  g3.t[1] = {xb, Wvb, vinit};
  g3.t[2] = {x0n, Wvb, cvx};
  gemm_bt3<<<dim3(64, 4, 3), 256, 0, stream>>>(g3, 512, 2048);

  // q scale folds rmsnorm*1.2, softmax 1/sqrt(D), and log2(e) for exp2-softmax
  const float qmult = 1.2f * 0.08838834764831845f * 1.4426950408889634f;
  post_qk<<<32768, 256, 0, stream>>>(q_pre, cosp, sinp, qh, NH, qmult);
  post_qk<<<8192, 256, 0, stream>>>(k_pre, cosp, sinp, kh, NKV, 1.2f);
  post_v<<<dim3(32, 16), 256, 0, stream>>>(vinit, cvx, av, bv, vth, vout);

  attn<<<dim3(16, 64), 256, 0, stream>>>(qh, kh, vth, att);

  gemm_bt<float><<<dim3(64, 16), 256, 0, stream>>>(att, Wpb, y, 2048, 2048);
}